// Round 8
// baseline (125.316 us; speedup 1.0000x reference)
//
#include <hip/hip_runtime.h>
#include <hip/hip_fp16.h>
#include <math.h>

// Fused GAT forward: scores -> edge softmax per dst row -> weighted gather-sum.
//
// Round-6 kernel (third submit; rounds 6-7 hit GPU-acquisition timeouts,
// never ran): head-partitioned XCD mapping, fixed.
//  * One head's fp16 slice = N*D*2B = 3.2MB < 4MiB/XCD L2. Table stored
//    head-major [H][N][D] fp16 in d_ws; head = (blockIdx&7)>>1 pins each
//    head's gathers to 2 XCDs (round-robin dispatch heuristic).
//  * cvt is WRITE-coalesced (round 5 had it backwards: scattered writes).
//  * Main kernel: 16-lane group per dst; col indices via per-lane int4
//    loads (no shfl in any address path); all 16 half2 gathers issued
//    back-to-back (raw half2 kept, cvt deferred to FMA) with
//    sched_barrier pinning loads ahead of the softmax VALU work.

#define GAT_H 4
#define GAT_D 32
#define GAT_DEG 16
#define GAT_NEG_SLOPE 0.2f

struct alignas(8) half4 { __half2 lo, hi; };

// ---- cvt: fp32 [N][H][D] -> fp16 head-major [H][N][D] ----
// thread = one float4 (4 feats). Writes linear in t -> fully coalesced.
// grid: ( ceil(n*8/256), H )
__global__ __launch_bounds__(256) void gat_cvt_kernel(
    const float4* __restrict__ in,   // [N][H][8] float4 view
    half4*        __restrict__ outp, // [H][N][8] half4 view
    int n)
{
    const int t = blockIdx.x * 256 + threadIdx.x;    // [0, n*8)
    const int h = blockIdx.y;
    if (t < n * 8) {
        const int nn = t >> 3, q = t & 7;
        const float4 v = in[(nn * GAT_H + h) * 8 + q];
        half4 o;
        o.lo = __floats2half2_rn(v.x, v.y);
        o.hi = __floats2half2_rn(v.z, v.w);
        outp[(size_t)h * n * 8 + t] = o;
    }
}

template <bool FP16>
__global__ __launch_bounds__(256, 4) void gat_main_kernel(
    const float*   __restrict__ attn_row,    // [N,H]
    const float*   __restrict__ attn_col,    // [N,H]
    const float2*  __restrict__ feat32,      // [N][H][16] float2 (fallback)
    const __half2* __restrict__ feat16,      // [H][N][16] half2 (d_ws)
    const int*     __restrict__ row_indptr,  // [N+1]
    const int*     __restrict__ col_indices, // [E]
    float2*        __restrict__ out,         // [N][H][16] float2 view
    int n, int nb)
{
    const int b   = blockIdx.x;
    const int xcd = b & 7;                    // round-robin block->XCD
    const int h   = xcd >> 1;                 // 2 XCDs per head
    const int j   = (b >> 3) * 2 + (xcd & 1); // 16-dst chunk within head
    if (j >= nb) return;

    const int lane = threadIdx.x & 63;
    const int wid  = threadIdx.x >> 6;
    const int g    = lane >> 4;               // dst group within wave
    const int e    = lane & 15;               // edge idx == half2 column
    const int dst  = j * 16 + wid * 4 + g;
    if (dst >= n) return;

    const int start = row_indptr[dst];
    const int deg   = row_indptr[dst + 1] - start;   // == 16 here

    // ---- all 16 col indices per lane (int4 loads, broadcast in group) ----
    int idx[GAT_DEG];
    {
        const int4* cip = reinterpret_cast<const int4*>(col_indices + start);
        #pragma unroll
        for (int q = 0; q < 4; ++q) {
            const int4 c = cip[q];
            idx[4*q+0] = c.x; idx[4*q+1] = c.y;
            idx[4*q+2] = c.z; idx[4*q+3] = c.w;
        }
    }

    // ---- issue ALL 16 feature gathers; keep raw half2 (no cvt -> no wait) --
    __half2 hv[GAT_DEG];
    float2  fv[GAT_DEG];
    #pragma unroll
    for (int k = 0; k < GAT_DEG; ++k) {
        if (FP16)
            hv[k] = feat16[((size_t)h * n + idx[k]) * 16 + e];
        else
            fv[k] = feat32[((size_t)idx[k] * GAT_H + h) * 16 + e];
    }
    __builtin_amdgcn_sched_barrier(0);   // pin loads ahead of softmax VALU

    // ---- softmax over this dst's 16 edges (lane e owns edge e) ----
    const float ar = attn_row[dst * GAT_H + h];
    float s = -INFINITY;
    if (e < deg) {
        const float x = ar + attn_col[idx[e] * GAT_H + h];
        s = (x > 0.0f) ? x : GAT_NEG_SLOPE * x;
    }
    float m = s;
    #pragma unroll
    for (int off = 1; off < 16; off <<= 1)
        m = fmaxf(m, __shfl_xor(m, off));

    const float ex = (e < deg) ? __expf(s - m) : 0.0f;

    float den = ex;
    #pragma unroll
    for (int off = 1; off < 16; off <<= 1)
        den += __shfl_xor(den, off);
    const float rden = __builtin_amdgcn_rcpf(den);

    // ---- weighted accumulate (alpha broadcast is an operand, not address) --
    const int base = lane & 48;
    float accx = 0.0f, accy = 0.0f;
    #pragma unroll
    for (int k = 0; k < GAT_DEG; ++k) {
        const float a = __shfl(ex, base + k);
        const float2 f = FP16 ? __half22float2(hv[k]) : fv[k];
        accx = fmaf(a, f.x, accx);
        accy = fmaf(a, f.y, accy);
    }

    out[((size_t)dst * GAT_H + h) * 16 + e] =
        make_float2(accx * rden, accy * rden);
}

extern "C" void kernel_launch(void* const* d_in, const int* in_sizes, int n_in,
                              void* d_out, int out_size, void* d_ws, size_t ws_size,
                              hipStream_t stream) {
    const float* attn_row    = (const float*)d_in[0];
    const float* attn_col    = (const float*)d_in[1];
    const float* in_feat     = (const float*)d_in[2];
    const int*   row_indptr  = (const int*)d_in[3];
    const int*   col_indices = (const int*)d_in[4];
    float2*      out         = (float2*)d_out;

    const int n      = in_sizes[0] / GAT_H;   // N nodes
    const int n_feat = in_sizes[2];           // N*H*D

    const int nb     = (n + 15) / 16;         // 16-dst chunks per head
    const int kmax   = (nb + 1) / 2;          // chunks per (head, parity)
    const int blocks = kmax * 8;

    const size_t fp16_bytes = (size_t)n_feat * sizeof(__half);
    if (ws_size >= fp16_bytes) {
        half4* feat_h = (half4*)d_ws;
        dim3 cgrid((n * 8 + 255) / 256, GAT_H);
        gat_cvt_kernel<<<cgrid, 256, 0, stream>>>(
            (const float4*)in_feat, feat_h, n);
        gat_main_kernel<true><<<blocks, 256, 0, stream>>>(
            attn_row, attn_col, (const float2*)in_feat, (const __half2*)feat_h,
            row_indptr, col_indices, out, n, nb);
    } else {
        gat_main_kernel<false><<<blocks, 256, 0, stream>>>(
            attn_row, attn_col, (const float2*)in_feat, (const __half2*)nullptr,
            row_indptr, col_indices, out, n, nb);
    }
}

// Round 10
// 117.256 us; speedup vs baseline: 1.0687x; 1.0687x over previous
//
#include <hip/hip_runtime.h>
#include <hip/hip_fp16.h>
#include <math.h>

// Fused GAT forward: scores -> edge softmax per dst row -> weighted gather-sum.
//
// Round-10 = round-9 with the compile fix (__builtin_nontemporal_load needs a
// native/ext-vector pointer, not HIP_vector_type float4).
//  * fp16 table, monolithic [N][H][D] in d_ws; wave = 1 dst x all 4 heads;
//    each gather = one fully-used 256B contiguous row, 16 issued back-to-back.
//  * Group softmax: lane q owns edge q (1 attn gather + 1 exp per lane,
//    was 16+16 in rounds 3/4 -> ~68% VALUBusy co-binding at 32us).
//    shfl_xor reduce within 16-lane head group; alpha enters FMAs via __shfl
//    as an operand only (never an address).
//  * Non-temporal out stores (25.6MB streamed once) so streaming writes
//    don't evict the 12.8MB fp16 gather table from L2; nt loads in cvt.
//  * attn gather issued BEFORE the 16 feature gathers -> softmax consumes it
//    at vmcnt(16) while feature loads are still in flight.

#define GAT_H 4
#define GAT_D 32
#define GAT_DEG 16
#define GAT_NEG_SLOPE 0.2f

struct alignas(8) half4 { __half2 lo, hi; };
typedef float floatx4 __attribute__((ext_vector_type(4)));

// ---- cvt: fp32 [N][H][D] -> fp16 [N][H][D], linear, fully coalesced ----
__global__ __launch_bounds__(256) void gat_cvt_kernel(
    const floatx4* __restrict__ in, half4* __restrict__ outp, int n4)
{
    const int t = blockIdx.x * 256 + threadIdx.x;
    if (t < n4) {
        const floatx4 v = __builtin_nontemporal_load(&in[t]);
        half4 o;
        o.lo = __floats2half2_rn(v.x, v.y);
        o.hi = __floats2half2_rn(v.z, v.w);
        outp[t] = o;
    }
}

template <bool FP16>
__global__ __launch_bounds__(256, 4) void gat_main_kernel(
    const float*   __restrict__ attn_row,    // [N,H]
    const float*   __restrict__ attn_col,    // [N,H]
    const float2*  __restrict__ feat32,      // [N][H][16] float2 (fallback)
    const __half2* __restrict__ feat16,      // [N][H][16] half2 (d_ws)
    const int*     __restrict__ row_indptr,  // [N+1]
    const int*     __restrict__ col_indices, // [E]
    float*         __restrict__ out,         // [N,H,D]
    int n)
{
    const int wave_id = (int)((blockIdx.x * (unsigned)blockDim.x + threadIdx.x) >> 6);
    const int lane    = threadIdx.x & 63;
    if (wave_id >= n) return;
    const int dst = wave_id;
    const int h   = lane >> 4;          // head
    const int q   = lane & 15;          // edge index == half2 feature column

    int start = row_indptr[dst];
    const int deg = row_indptr[dst + 1] - start;     // == 16 here
    start = __builtin_amdgcn_readfirstlane(start);   // wave-uniform -> s_load

    // ---- 16 col indices from uniform int4 loads (scalar, broadcast) ----
    int idx[GAT_DEG];
    {
        const int4* cip = reinterpret_cast<const int4*>(col_indices + start);
        #pragma unroll
        for (int p = 0; p < 4; ++p) {
            const int4 c = cip[p];
            idx[4*p+0] = c.x; idx[4*p+1] = c.y;
            idx[4*p+2] = c.z; idx[4*p+3] = c.w;
        }
    }

    // ---- issue attn gather FIRST (softmax consumes it at vmcnt(16)) ----
    const float ac = attn_col[idx[q] * GAT_H + h];   // lane q: edge q, head h
    const float ar = attn_row[dst * GAT_H + h];

    // ---- then ALL 16 feature gathers back-to-back (256B rows, in flight) --
    __half2 hv[GAT_DEG];
    float2  fv[GAT_DEG];
    #pragma unroll
    for (int k = 0; k < GAT_DEG; ++k) {
        const size_t off = (size_t)idx[k] * (GAT_H * GAT_D / 2) + h * 16 + q;
        if (FP16) hv[k] = feat16[off];
        else      fv[k] = feat32[off];
    }

    // ---- group softmax: lane q owns edge q (1 exp/lane) ----
    float s = -INFINITY;
    if (q < deg) {
        const float x = ar + ac;
        s = (x > 0.0f) ? x : GAT_NEG_SLOPE * x;
    }
    float m = s;
    #pragma unroll
    for (int off = 1; off < 16; off <<= 1)
        m = fmaxf(m, __shfl_xor(m, off));

    const float ex = (q < deg) ? __expf(s - m) : 0.0f;

    float den = ex;
    #pragma unroll
    for (int off = 1; off < 16; off <<= 1)
        den += __shfl_xor(den, off);
    const float rden = __builtin_amdgcn_rcpf(den);

    // ---- weighted accumulate; alpha broadcast is an FMA operand only ----
    const int base = lane & 48;     // first lane of my head group
    float accx = 0.0f, accy = 0.0f;
    #pragma unroll
    for (int k = 0; k < GAT_DEG; ++k) {
        const float a  = __shfl(ex, base + k);
        const float2 f = FP16 ? __half22float2(hv[k]) : fv[k];
        accx = fmaf(a, f.x, accx);
        accy = fmaf(a, f.y, accy);
    }

    // ---- non-temporal out store (streamed once; don't evict the table) ----
    union { float2 f2; double d; } r;
    r.f2 = make_float2(accx * rden, accy * rden);
    double* optr = reinterpret_cast<double*>(out) +
                   ((size_t)dst * GAT_H + h) * 16 + q;
    __builtin_nontemporal_store(r.d, optr);
}

extern "C" void kernel_launch(void* const* d_in, const int* in_sizes, int n_in,
                              void* d_out, int out_size, void* d_ws, size_t ws_size,
                              hipStream_t stream) {
    const float* attn_row    = (const float*)d_in[0];
    const float* attn_col    = (const float*)d_in[1];
    const float* in_feat     = (const float*)d_in[2];
    const int*   row_indptr  = (const int*)d_in[3];
    const int*   col_indices = (const int*)d_in[4];
    float*       out         = (float*)d_out;

    const int n      = in_sizes[0] / GAT_H;   // N nodes
    const int n_feat = in_sizes[2];           // N*H*D

    const int threads = 256;                  // 4 waves = 4 dsts / block
    const int blocks  = (n + 3) / 4;

    const size_t fp16_bytes = (size_t)n_feat * sizeof(__half);
    if (ws_size >= fp16_bytes) {
        half4* feat_h = (half4*)d_ws;
        const int n4 = n_feat / 4;
        gat_cvt_kernel<<<(n4 + 255) / 256, 256, 0, stream>>>(
            (const floatx4*)in_feat, feat_h, n4);
        gat_main_kernel<true><<<blocks, threads, 0, stream>>>(
            attn_row, attn_col, (const float2*)in_feat, (const __half2*)feat_h,
            row_indptr, col_indices, out, n);
    } else {
        gat_main_kernel<false><<<blocks, threads, 0, stream>>>(
            attn_row, attn_col, (const float2*)in_feat, (const __half2*)nullptr,
            row_indptr, col_indices, out, n);
    }
}